// Round 8
// baseline (472.180 us; speedup 1.0000x reference)
//
#include <hip/hip_runtime.h>
#include <cfloat>

#define NPTS 8192

typedef __attribute__((ext_vector_type(8))) short short8;
typedef __attribute__((ext_vector_type(4))) short short4v;
typedef __attribute__((ext_vector_type(4))) float f32x4;

__device__ inline unsigned short f2bf(float f) {
    unsigned u = __builtin_bit_cast(unsigned, f);
    u += 0x7fffu + ((u >> 16) & 1u);
    return (unsigned short)(u >> 16);
}
__device__ inline float bf2f(unsigned short h) {
    unsigned u = ((unsigned)h) << 16;
    return __builtin_bit_cast(float, u);
}

// ---------------------------------------------------------------------------
// Kernel 0: fused prep — convert d2/g1/g2 weights to bf16 AND pack candidate
// float4 (x,y,z,||p||^2).
// ---------------------------------------------------------------------------
__global__ void prep_kernel(const float* __restrict__ d2_w,
                            const float* __restrict__ g1_w,
                            const float* __restrict__ g2_w,
                            unsigned short* __restrict__ wd2,
                            unsigned short* __restrict__ wg1,
                            unsigned short* __restrict__ wg2,
                            const float* __restrict__ xyz,
                            float4* __restrict__ candp)
{
    int i = blockIdx.x * 256 + threadIdx.x;          // 0 .. 65535
    if (i < 49152) {
        int sel = i >> 14, off = i & 16383;
        const float* s = (sel == 0) ? d2_w : (sel == 1) ? g1_w : g2_w;
        unsigned short* d = (sel == 0) ? wd2 : (sel == 1) ? wg1 : wg2;
        d[off] = f2bf(s[off]);
    } else {
        int j = i - 49152;                           // 0..16383
        int b = j >> 13, n = j & 8191;
        const float* xg = xyz + (long)b * 3 * NPTS;
        float x = xg[n], y = xg[NPTS + n], z = xg[2*NPTS + n];
        float4 c; c.x = x; c.y = y; c.z = z;
        c.w = fmaf(x, x, fmaf(y, y, z * z));
        candp[j] = c;
    }
}

// ---------------------------------------------------------------------------
// Kernel 1: x = fc1(feat); q,k,v = x @ {wq,wk,wv}.T  -> bf16, PERMUTED layout:
// channel c stored at position (c&15)*8 + (c>>4).
// ---------------------------------------------------------------------------
__global__ __launch_bounds__(128, 2)
void proj_kernel(const float* __restrict__ feat,
                 const float* __restrict__ fc1_w, const float* __restrict__ fc1_b,
                 const float* __restrict__ wq, const float* __restrict__ wk,
                 const float* __restrict__ wv,
                 unsigned short* __restrict__ qb, unsigned short* __restrict__ kbuf,
                 unsigned short* __restrict__ vbuf)
{
    __shared__ float fl[8][3];
    __shared__ float xl[8][128];
    const int c = threadIdx.x;
    const long base = (long)blockIdx.x * 8;

    if (c < 24) {
        int p = c / 3, d = c % 3;
        long pt = base + p;
        int b = (int)(pt >> 13), n = (int)(pt & 8191);
        fl[p][d] = feat[((long)b * 3 + d) * NPTS + n];
    }
    __syncthreads();

    float w0 = fc1_w[c*3+0], w1 = fc1_w[c*3+1], w2 = fc1_w[c*3+2], b0 = fc1_b[c];
    #pragma unroll
    for (int p = 0; p < 8; ++p)
        xl[p][c] = fmaf(w0, fl[p][0], fmaf(w1, fl[p][1], fmaf(w2, fl[p][2], b0)));
    __syncthreads();

    float aq[8], ak[8], av[8];
    #pragma unroll
    for (int p = 0; p < 8; ++p) { aq[p] = 0.f; ak[p] = 0.f; av[p] = 0.f; }

    const float4* wq4 = (const float4*)(wq + c*128);
    const float4* wk4 = (const float4*)(wk + c*128);
    const float4* wv4 = (const float4*)(wv + c*128);
    for (int i4 = 0; i4 < 32; ++i4) {
        float4 a = wq4[i4], bw = wk4[i4], cw = wv4[i4];
        #pragma unroll
        for (int p = 0; p < 8; ++p) {
            float4 x = *(const float4*)&xl[p][i4*4];
            aq[p] = fmaf(a.x,x.x, fmaf(a.y,x.y, fmaf(a.z,x.z, fmaf(a.w,x.w, aq[p]))));
            ak[p] = fmaf(bw.x,x.x,fmaf(bw.y,x.y,fmaf(bw.z,x.z,fmaf(bw.w,x.w, ak[p]))));
            av[p] = fmaf(cw.x,x.x,fmaf(cw.y,x.y,fmaf(cw.z,x.z,fmaf(cw.w,x.w, av[p]))));
        }
    }
    const int perm = (c & 15) * 8 + (c >> 4);
    #pragma unroll
    for (int p = 0; p < 8; ++p) {
        long pt = base + p;
        qb[pt*128 + perm]   = f2bf(aq[p]);
        kbuf[pt*128 + perm] = f2bf(ak[p]);
        vbuf[pt*128 + perm] = f2bf(av[p]);
    }
}

// ---------------------------------------------------------------------------
// Kernel 2b: KNN partial v4 — cross-wave threshold sharing.
// Block = 64 queries x 2048-cand chunk; 4 waves stream disjoint 512-cand
// subranges (lane = query). Each wave publishes its running 16th-best to LDS;
// push threshold = min(own ad[15], min over waves' published ad[15]).
// Discards are certified-safe (16 better candidates known), so partials'
// union still contains the true top-16; rank merge unchanged.
// ---------------------------------------------------------------------------
#define RINGN 15
#define RSTR 264
#define DRTH 8

__global__ __launch_bounds__(256, 4)
void knn_part_kernel(const float4* __restrict__ cand,
                     float* __restrict__ part_d, int* __restrict__ part_i)
{
    __shared__ float smem[8320];               // ring (pre-sync) / mg (post)
    __shared__ float thr_sh[4][64];            // per-wave published ad[15]
    float* ringd = smem;                       // [RINGN][RSTR] = 3960 floats
    int*   ringi = (int*)(smem + RINGN*RSTR);  // + 3960 = 7920 <= 8320
    float2* mg   = (float2*)smem;              // [64][65] (post-sync reuse)

    const int t  = threadIdx.x;
    const int ql = t & 63, wv = t >> 6;
    const int qsg = blockIdx.x >> 2;      // 0..255
    const int ck  = blockIdx.x & 3;       // chunk of 2048
    const int q   = qsg * 64 + ql;        // global query id
    const int b   = q >> 13;

    const float4* cp = cand + (b << 13) + ck * 2048 + wv * 512;
    const int ibase = ck * 2048 + wv * 512;
    float4 qc = cand[(b << 13) + (q & 8191)];
    const float qx2 = -2.f * qc.x, qy2 = -2.f * qc.y, qz2 = -2.f * qc.z;

    thr_sh[wv][ql] = FLT_MAX;
    __syncthreads();

    float ad[16];
    int   ai[16];
    #pragma unroll
    for (int i = 0; i < 16; ++i) { ad[i] = FLT_MAX; ai[i] = -1; }
    int rc = 0;

    auto insert16 = [&](float d, int idx) {
        bool hi = true;
        #pragma unroll
        for (int sl = 15; sl >= 1; --sl) {
            bool sw = d < ad[sl-1];
            float nd = sw ? ad[sl-1] : (hi ? d   : ad[sl]);
            int   ni = sw ? ai[sl-1] : (hi ? idx : ai[sl]);
            ad[sl] = nd; ai[sl] = ni;
            hi = hi && sw;
        }
        ad[0] = hi ? d   : ad[0];
        ai[0] = hi ? idx : ai[0];
    };
    auto drain = [&]() {
        for (int w = 0; w < rc; ++w) {
            float d = ringd[w * RSTR + t];
            int idx = ringi[w * RSTR + t];
            if (d < ad[15]) insert16(d, idx);
        }
        rc = 0;
    };
    auto dist = [&](float4 c) {
        return fmaf(qx2, c.x, fmaf(qy2, c.y, fmaf(qz2, c.z, c.w)));
    };

    // seed: first 16 candidates of this wave's range
    #pragma unroll
    for (int m = 0; m < 16; ++m) insert16(dist(cp[m]), ibase + m);

    float Tcur = FLT_MAX;
    float4 cur[8], nxt[8];
    #pragma unroll
    for (int u = 0; u < 8; ++u) cur[u] = cp[16 + u];
    for (int m = 16; m < 512; m += 8) {
        if ((m & 31) == 16) {            // every 4 groups: publish + refresh
            thr_sh[wv][ql] = ad[15];
            Tcur = fminf(fminf(thr_sh[0][ql], thr_sh[1][ql]),
                         fminf(thr_sh[2][ql], thr_sh[3][ql]));
        }
        if (m + 8 < 512) {
            #pragma unroll
            for (int u = 0; u < 8; ++u) nxt[u] = cp[m + 8 + u];
        }
        float dv[8];
        #pragma unroll
        for (int u = 0; u < 8; ++u) dv[u] = dist(cur[u]);
        float thr = fminf(ad[15], Tcur);
        int hm = 0;
        #pragma unroll
        for (int u = 0; u < 8; ++u) hm |= (dv[u] < thr) ? (1 << u) : 0;
        if (__any(hm != 0)) {
            #pragma unroll
            for (int u = 0; u < 8; ++u) {
                if (hm & (1 << u)) {
                    ringd[rc * RSTR + t] = dv[u];
                    ringi[rc * RSTR + t] = ibase + m + u;
                    ++rc;
                }
            }
            if (__any(rc >= DRTH)) drain();
        }
        #pragma unroll
        for (int u = 0; u < 8; ++u) cur[u] = nxt[u];
    }
    drain();
    __syncthreads();

    #pragma unroll
    for (int i = 0; i < 16; ++i) {
        float2 e; e.x = ad[i]; e.y = __builtin_bit_cast(float, ai[i]);
        mg[ql * 65 + wv * 16 + i] = e;
    }
    __syncthreads();

    int rank[16];
    #pragma unroll
    for (int i = 0; i < 16; ++i) rank[i] = 0;
    for (int j = 0; j < 64; ++j) {
        float2 e = mg[ql * 65 + j];
        float dj = e.x; int ij = __builtin_bit_cast(int, e.y);
        #pragma unroll
        for (int i = 0; i < 16; ++i)
            rank[i] += ((dj < ad[i]) || (dj == ad[i] && ij < ai[i])) ? 1 : 0;
    }
    const long pb = ((long)q * 4 + ck) * 16;
    #pragma unroll
    for (int i = 0; i < 16; ++i)
        if (rank[i] < 16) {
            part_d[pb + rank[i]] = ad[i];
            part_i[pb + rank[i]] = ai[i];
        }
}

// ---------------------------------------------------------------------------
// Kernel 2c: merge 4 partial top-16 -> final top-16 (rank select, idx ties)
// NOTE: partials may contain FLT_MAX fillers (pruned entries) — harmless,
// they rank >= 16 whenever 16 real candidates exist (always: 2048/chunk).
// ---------------------------------------------------------------------------
__global__ __launch_bounds__(256, 4)
void knn_merge_kernel(const float* __restrict__ part_d,
                      const int* __restrict__ part_i, int* __restrict__ knn)
{
    __shared__ float sd[4][64];
    __shared__ int   si[4][64];
    const int t = threadIdx.x;
    const int ql = t >> 6, e = t & 63;
    const long q = (long)blockIdx.x * 4 + ql;
    float d = part_d[q * 64 + e];
    int idx = part_i[q * 64 + e];
    sd[ql][e] = d; si[ql][e] = idx;
    __syncthreads();
    int rank = 0;
    #pragma unroll 8
    for (int j = 0; j < 64; ++j) {
        float dj = sd[ql][j];
        rank += ((dj < d) || (dj == d && si[ql][j] < idx)) ? 1 : 0;
    }
    if (rank < 16) knn[q * 16 + rank] = idx;
}

// ---------------------------------------------------------------------------
// Kernel 3: fused attention, MFMA 16x16x32 bf16 (unchanged from R6/R7).
// ---------------------------------------------------------------------------
__device__ inline int hswz(int r, int c) {           // hbuf swizzled index
    return r * 128 + (c ^ ((r & 7) << 4));
}

__global__ __launch_bounds__(256, 2)
void attn_kernel(const float* __restrict__ xyz, const float* __restrict__ feat,
                 const float* __restrict__ d1_w, const float* __restrict__ d1_b,
                 const float* __restrict__ d2_b, const float* __restrict__ g1_b,
                 const float* __restrict__ g2_b,
                 const float* __restrict__ fc2_w, const float* __restrict__ fc2_b,
                 const unsigned short* __restrict__ qb,
                 const unsigned short* __restrict__ kb,
                 const unsigned short* __restrict__ vb,
                 const unsigned short* __restrict__ wd2,
                 const unsigned short* __restrict__ wg1,
                 const unsigned short* __restrict__ wg2,
                 const int* __restrict__ knn, float* __restrict__ out)
{
    __shared__ unsigned short hbuf[128 * 128];  // h1 -> h -> gh (swizzled)
    __shared__ float relb[128 * 4];
    __shared__ float resl[8 * 128];
    __shared__ int   idxs[128];

    const int t    = threadIdx.x;
    const int wave = t >> 6, lane = t & 63;
    const int quad = lane >> 4, l15 = lane & 15;
    const long pbase = (long)blockIdx.x * 8;
    const int b = (int)(pbase >> 13);
    const long bofs = (long)b * NPTS;

    if (t < 128) idxs[t] = knn[(pbase + (t >> 4)) * 16 + (t & 15)];
    __syncthreads();

    if (t < 128) {
        int r = t;
        int nn = (int)((pbase + (r >> 4)) & 8191);
        int m = idxs[r];
        const float* xg = xyz + (long)b * 3 * NPTS;
        relb[r*4+0] = xg[nn]        - xg[m];
        relb[r*4+1] = xg[NPTS+nn]   - xg[NPTS+m];
        relb[r*4+2] = xg[2*NPTS+nn] - xg[2*NPTS+m];
        relb[r*4+3] = 0.f;
    }
    short8 qvv[2], kgv[2][4], vgv[2][4];
    #pragma unroll
    for (int mt = 0; mt < 2; ++mt) {
        qvv[mt] = *(const short8*)(qb + (size_t)(pbase + wave*2 + mt) * 128 + l15*8);
        #pragma unroll
        for (int r = 0; r < 4; ++r) {
            int R = (wave*2 + mt)*16 + quad*4 + r;
            kgv[mt][r] = *(const short8*)(kb + (size_t)(bofs + idxs[R]) * 128 + l15*8);
            vgv[mt][r] = *(const short8*)(vb + (size_t)(bofs + idxs[R]) * 128 + l15*8);
        }
    }
    __syncthreads();

    {
        int c8 = t & 15, r0 = t >> 4;
        float w0[8], w1[8], w2[8], bb[8];
        #pragma unroll
        for (int k = 0; k < 8; ++k) {
            int c = c8*8 + k;
            w0[k] = d1_w[c*3]; w1[k] = d1_w[c*3+1]; w2[k] = d1_w[c*3+2];
            bb[k] = d1_b[c];
        }
        #pragma unroll
        for (int i = 0; i < 8; ++i) {
            int row = r0 + 16*i;
            float4 rl = *(const float4*)&relb[row*4];
            short8 hv;
            #pragma unroll
            for (int k = 0; k < 8; ++k) {
                float v = fmaf(w0[k], rl.x, fmaf(w1[k], rl.y, fmaf(w2[k], rl.z, bb[k])));
                hv[k] = (short)f2bf(fmaxf(v, 0.f));
            }
            *(short8*)&hbuf[hswz(row, c8*8)] = hv;
        }
    }
    __syncthreads();

    const int wrow0 = wave * 32;
    short8 A[2][4];
    f32x4 acc[2];

    auto loadA = [&]() {
        #pragma unroll
        for (int mt = 0; mt < 2; ++mt)
            #pragma unroll
            for (int kk = 0; kk < 4; ++kk)
                A[mt][kk] = *(const short8*)&hbuf[hswz(wrow0 + mt*16 + l15, kk*32 + quad*8)];
    };

    unsigned posp[2][8][2];   // packed bf16 pos fragments

    // ============ GEMM 1: pos = h1 @ d2.T + b; h = q - kg + pos ============
    loadA();
    #pragma unroll
    for (int n0 = 0; n0 < 8; ++n0) {
        const unsigned short* wp = wd2 + (n0*16 + l15) * 128 + quad*8;
        short8 B0 = *(const short8*)(wp);
        short8 B1 = *(const short8*)(wp + 32);
        short8 B2 = *(const short8*)(wp + 64);
        short8 B3 = *(const short8*)(wp + 96);
        acc[0] = (f32x4){0.f,0.f,0.f,0.f};
        acc[1] = (f32x4){0.f,0.f,0.f,0.f};
        #pragma unroll
        for (int mt = 0; mt < 2; ++mt) {
            acc[mt] = __builtin_amdgcn_mfma_f32_16x16x32_bf16(A[mt][0], B0, acc[mt], 0, 0, 0);
            acc[mt] = __builtin_amdgcn_mfma_f32_16x16x32_bf16(A[mt][1], B1, acc[mt], 0, 0, 0);
            acc[mt] = __builtin_amdgcn_mfma_f32_16x16x32_bf16(A[mt][2], B2, acc[mt], 0, 0, 0);
            acc[mt] = __builtin_amdgcn_mfma_f32_16x16x32_bf16(A[mt][3], B3, acc[mt], 0, 0, 0);
        }
        int c = n0*16 + l15;
        float bb = d2_b[c];
        #pragma unroll
        for (int mt = 0; mt < 2; ++mt) {
            float qv = bf2f((unsigned short)qvv[mt][n0]);
            float p0 = acc[mt][0] + bb, p1 = acc[mt][1] + bb;
            float p2 = acc[mt][2] + bb, p3 = acc[mt][3] + bb;
            posp[mt][n0][0] = (unsigned)f2bf(p0) | ((unsigned)f2bf(p1) << 16);
            posp[mt][n0][1] = (unsigned)f2bf(p2) | ((unsigned)f2bf(p3) << 16);
            int rb = wrow0 + mt*16 + quad*4;
            hbuf[hswz(rb+0, c)] = f2bf(qv - bf2f((unsigned short)kgv[mt][0][n0]) + p0);
            hbuf[hswz(rb+1, c)] = f2bf(qv - bf2f((unsigned short)kgv[mt][1][n0]) + p1);
            hbuf[hswz(rb+2, c)] = f2bf(qv - bf2f((unsigned short)kgv[mt][2][n0]) + p2);
            hbuf[hswz(rb+3, c)] = f2bf(qv - bf2f((unsigned short)kgv[mt][3][n0]) + p3);
        }
    }

    // ============ GEMM 2: gh = relu(h @ g1.T + b) ============
    loadA();
    #pragma unroll
    for (int n0 = 0; n0 < 8; ++n0) {
        const unsigned short* wp = wg1 + (n0*16 + l15) * 128 + quad*8;
        short8 B0 = *(const short8*)(wp);
        short8 B1 = *(const short8*)(wp + 32);
        short8 B2 = *(const short8*)(wp + 64);
        short8 B3 = *(const short8*)(wp + 96);
        acc[0] = (f32x4){0.f,0.f,0.f,0.f};
        acc[1] = (f32x4){0.f,0.f,0.f,0.f};
        #pragma unroll
        for (int mt = 0; mt < 2; ++mt) {
            acc[mt] = __builtin_amdgcn_mfma_f32_16x16x32_bf16(A[mt][0], B0, acc[mt], 0, 0, 0);
            acc[mt] = __builtin_amdgcn_mfma_f32_16x16x32_bf16(A[mt][1], B1, acc[mt], 0, 0, 0);
            acc[mt] = __builtin_amdgcn_mfma_f32_16x16x32_bf16(A[mt][2], B2, acc[mt], 0, 0, 0);
            acc[mt] = __builtin_amdgcn_mfma_f32_16x16x32_bf16(A[mt][3], B3, acc[mt], 0, 0, 0);
        }
        int c = n0*16 + l15;
        float bb = g1_b[c];
        #pragma unroll
        for (int mt = 0; mt < 2; ++mt) {
            int rb = wrow0 + mt*16 + quad*4;
            #pragma unroll
            for (int r = 0; r < 4; ++r)
                hbuf[hswz(rb+r, c)] = f2bf(fmaxf(acc[mt][r] + bb, 0.f));
        }
    }

    // ==== GEMM 3: logits -> softmax over K -> res = sum attn*(v+pos) ====
    loadA();
    const float sc = 0.08838834764831845f;
    #pragma unroll
    for (int n0 = 0; n0 < 8; ++n0) {
        const unsigned short* wp = wg2 + (n0*16 + l15) * 128 + quad*8;
        short8 B0 = *(const short8*)(wp);
        short8 B1 = *(const short8*)(wp + 32);
        short8 B2 = *(const short8*)(wp + 64);
        short8 B3 = *(const short8*)(wp + 96);
        acc[0] = (f32x4){0.f,0.f,0.f,0.f};
        acc[1] = (f32x4){0.f,0.f,0.f,0.f};
        #pragma unroll
        for (int mt = 0; mt < 2; ++mt) {
            acc[mt] = __builtin_amdgcn_mfma_f32_16x16x32_bf16(A[mt][0], B0, acc[mt], 0, 0, 0);
            acc[mt] = __builtin_amdgcn_mfma_f32_16x16x32_bf16(A[mt][1], B1, acc[mt], 0, 0, 0);
            acc[mt] = __builtin_amdgcn_mfma_f32_16x16x32_bf16(A[mt][2], B2, acc[mt], 0, 0, 0);
            acc[mt] = __builtin_amdgcn_mfma_f32_16x16x32_bf16(A[mt][3], B3, acc[mt], 0, 0, 0);
        }
        int c = n0*16 + l15;
        float bb = g2_b[c];
        #pragma unroll
        for (int mt = 0; mt < 2; ++mt) {
            float e0 = (acc[mt][0] + bb) * sc;
            float e1 = (acc[mt][1] + bb) * sc;
            float e2 = (acc[mt][2] + bb) * sc;
            float e3 = (acc[mt][3] + bb) * sc;
            float mx = fmaxf(fmaxf(e0, e1), fmaxf(e2, e3));
            mx = fmaxf(mx, __shfl_xor(mx, 16));
            mx = fmaxf(mx, __shfl_xor(mx, 32));
            e0 = __expf(e0 - mx); e1 = __expf(e1 - mx);
            e2 = __expf(e2 - mx); e3 = __expf(e3 - mx);
            float ssum = e0 + e1 + e2 + e3;
            ssum += __shfl_xor(ssum, 16);
            ssum += __shfl_xor(ssum, 32);
            float p0 = bf2f((unsigned short)(posp[mt][n0][0] & 0xffff));
            float p1 = bf2f((unsigned short)(posp[mt][n0][0] >> 16));
            float p2 = bf2f((unsigned short)(posp[mt][n0][1] & 0xffff));
            float p3 = bf2f((unsigned short)(posp[mt][n0][1] >> 16));
            float p = e0 * (bf2f((unsigned short)vgv[mt][0][n0]) + p0)
                    + e1 * (bf2f((unsigned short)vgv[mt][1][n0]) + p1)
                    + e2 * (bf2f((unsigned short)vgv[mt][2][n0]) + p2)
                    + e3 * (bf2f((unsigned short)vgv[mt][3][n0]) + p3);
            p += __shfl_xor(p, 16);
            p += __shfl_xor(p, 32);
            if (quad == 0) resl[(wave*2 + mt)*128 + c] = p / ssum;
        }
    }
    __syncthreads();

    // ---- epilogue: out = res @ fc2.T + b + feat ----
    {
        int pt = t >> 5, j = t & 31;
        #pragma unroll
        for (int dp = 0; dp < 3; ++dp) {
            float part = 0.f;
            #pragma unroll
            for (int i = 0; i < 4; ++i) {
                int cc = j + 32*i;
                part = fmaf(fc2_w[dp*128 + cc], resl[pt*128 + cc], part);
            }
            part += __shfl_down(part, 16, 32);
            part += __shfl_down(part, 8, 32);
            part += __shfl_down(part, 4, 32);
            part += __shfl_down(part, 2, 32);
            part += __shfl_down(part, 1, 32);
            if (j == 0) {
                int nn = (int)((pbase + pt) & 8191);
                long o = ((long)b*3 + dp) * NPTS + nn;
                out[o] = part + fc2_b[dp] + feat[o];
            }
        }
    }
}

// ---------------------------------------------------------------------------
extern "C" void kernel_launch(void* const* d_in, const int* in_sizes, int n_in,
                              void* d_out, int out_size, void* d_ws, size_t ws_size,
                              hipStream_t stream)
{
    const float* xyz   = (const float*)d_in[0];
    const float* feat  = (const float*)d_in[1];
    const float* fc1_w = (const float*)d_in[2];
    const float* fc1_b = (const float*)d_in[3];
    const float* fc2_w = (const float*)d_in[4];
    const float* fc2_b = (const float*)d_in[5];
    const float* d1_w  = (const float*)d_in[6];
    const float* d1_b  = (const float*)d_in[7];
    const float* d2_w  = (const float*)d_in[8];
    const float* d2_b  = (const float*)d_in[9];
    const float* g1_w  = (const float*)d_in[10];
    const float* g1_b  = (const float*)d_in[11];
    const float* g2_w  = (const float*)d_in[12];
    const float* g2_b  = (const float*)d_in[13];
    const float* wq_w  = (const float*)d_in[14];
    const float* wk_w  = (const float*)d_in[15];
    const float* wv_w  = (const float*)d_in[16];
    float* out = (float*)d_out;

    unsigned short* qb  = (unsigned short*)d_ws;      // 16384*128 bf16 (permuted)
    unsigned short* kb  = qb + (size_t)16384*128;
    unsigned short* vb  = kb + (size_t)16384*128;
    unsigned short* wd2 = vb + (size_t)16384*128;     // 128*128 bf16 each
    unsigned short* wg1 = wd2 + 16384;
    unsigned short* wg2 = wg1 + 16384;
    int*   knn_ws = (int*)(wg2 + 16384);              // 16384*16 i32
    float4* cand  = (float4*)(knn_ws + (size_t)16384*16);   // 16384 float4
    float* part_d = (float*)(cand + 16384);           // 16384*64 f32
    int*   part_i = (int*)(part_d + (size_t)16384*64);// 16384*64 i32

    hipLaunchKernelGGL(prep_kernel, dim3(256), dim3(256), 0, stream,
                       d2_w, g1_w, g2_w, wd2, wg1, wg2, xyz, cand);
    hipLaunchKernelGGL(knn_part_kernel, dim3(1024), dim3(256), 0, stream,
                       cand, part_d, part_i);
    hipLaunchKernelGGL(knn_merge_kernel, dim3(4096), dim3(256), 0, stream,
                       part_d, part_i, knn_ws);
    hipLaunchKernelGGL(proj_kernel, dim3(2048), dim3(128), 0, stream,
                       feat, fc1_w, fc1_b, wq_w, wk_w, wv_w, qb, kb, vb);
    hipLaunchKernelGGL(attn_kernel, dim3(2048), dim3(256), 0, stream,
                       xyz, feat, d1_w, d1_b, d2_b, g1_b, g2_b, fc2_w, fc2_b,
                       qb, kb, vb, wd2, wg1, wg2, knn_ws, out);
}

// Round 9
// 464.393 us; speedup vs baseline: 1.0168x; 1.0168x over previous
//
#include <hip/hip_runtime.h>
#include <cfloat>

#define NPTS 8192

typedef __attribute__((ext_vector_type(8))) short short8;
typedef __attribute__((ext_vector_type(4))) short short4v;
typedef __attribute__((ext_vector_type(4))) float f32x4;

__device__ inline unsigned short f2bf(float f) {
    unsigned u = __builtin_bit_cast(unsigned, f);
    u += 0x7fffu + ((u >> 16) & 1u);
    return (unsigned short)(u >> 16);
}
__device__ inline float bf2f(unsigned short h) {
    unsigned u = ((unsigned)h) << 16;
    return __builtin_bit_cast(float, u);
}

// ---------------------------------------------------------------------------
// Kernel 0: fused prep — convert d2/g1/g2 weights to bf16 AND pack candidate
// float4 (x,y,z,||p||^2).
// ---------------------------------------------------------------------------
__global__ void prep_kernel(const float* __restrict__ d2_w,
                            const float* __restrict__ g1_w,
                            const float* __restrict__ g2_w,
                            unsigned short* __restrict__ wd2,
                            unsigned short* __restrict__ wg1,
                            unsigned short* __restrict__ wg2,
                            const float* __restrict__ xyz,
                            float4* __restrict__ candp)
{
    int i = blockIdx.x * 256 + threadIdx.x;          // 0 .. 65535
    if (i < 49152) {
        int sel = i >> 14, off = i & 16383;
        const float* s = (sel == 0) ? d2_w : (sel == 1) ? g1_w : g2_w;
        unsigned short* d = (sel == 0) ? wd2 : (sel == 1) ? wg1 : wg2;
        d[off] = f2bf(s[off]);
    } else {
        int j = i - 49152;                           // 0..16383
        int b = j >> 13, n = j & 8191;
        const float* xg = xyz + (long)b * 3 * NPTS;
        float x = xg[n], y = xg[NPTS + n], z = xg[2*NPTS + n];
        float4 c; c.x = x; c.y = y; c.z = z;
        c.w = fmaf(x, x, fmaf(y, y, z * z));
        candp[j] = c;
    }
}

// ---------------------------------------------------------------------------
// Kernel 1: x = fc1(feat); q,k,v = x @ {wq,wk,wv}.T  -> bf16, PERMUTED layout:
// channel c stored at position (c&15)*8 + (c>>4).
// ---------------------------------------------------------------------------
__global__ __launch_bounds__(128, 2)
void proj_kernel(const float* __restrict__ feat,
                 const float* __restrict__ fc1_w, const float* __restrict__ fc1_b,
                 const float* __restrict__ wq, const float* __restrict__ wk,
                 const float* __restrict__ wv,
                 unsigned short* __restrict__ qb, unsigned short* __restrict__ kbuf,
                 unsigned short* __restrict__ vbuf)
{
    __shared__ float fl[8][3];
    __shared__ float xl[8][128];
    const int c = threadIdx.x;
    const long base = (long)blockIdx.x * 8;

    if (c < 24) {
        int p = c / 3, d = c % 3;
        long pt = base + p;
        int b = (int)(pt >> 13), n = (int)(pt & 8191);
        fl[p][d] = feat[((long)b * 3 + d) * NPTS + n];
    }
    __syncthreads();

    float w0 = fc1_w[c*3+0], w1 = fc1_w[c*3+1], w2 = fc1_w[c*3+2], b0 = fc1_b[c];
    #pragma unroll
    for (int p = 0; p < 8; ++p)
        xl[p][c] = fmaf(w0, fl[p][0], fmaf(w1, fl[p][1], fmaf(w2, fl[p][2], b0)));
    __syncthreads();

    float aq[8], ak[8], av[8];
    #pragma unroll
    for (int p = 0; p < 8; ++p) { aq[p] = 0.f; ak[p] = 0.f; av[p] = 0.f; }

    const float4* wq4 = (const float4*)(wq + c*128);
    const float4* wk4 = (const float4*)(wk + c*128);
    const float4* wv4 = (const float4*)(wv + c*128);
    for (int i4 = 0; i4 < 32; ++i4) {
        float4 a = wq4[i4], bw = wk4[i4], cw = wv4[i4];
        #pragma unroll
        for (int p = 0; p < 8; ++p) {
            float4 x = *(const float4*)&xl[p][i4*4];
            aq[p] = fmaf(a.x,x.x, fmaf(a.y,x.y, fmaf(a.z,x.z, fmaf(a.w,x.w, aq[p]))));
            ak[p] = fmaf(bw.x,x.x,fmaf(bw.y,x.y,fmaf(bw.z,x.z,fmaf(bw.w,x.w, ak[p]))));
            av[p] = fmaf(cw.x,x.x,fmaf(cw.y,x.y,fmaf(cw.z,x.z,fmaf(cw.w,x.w, av[p]))));
        }
    }
    const int perm = (c & 15) * 8 + (c >> 4);
    #pragma unroll
    for (int p = 0; p < 8; ++p) {
        long pt = base + p;
        qb[pt*128 + perm]   = f2bf(aq[p]);
        kbuf[pt*128 + perm] = f2bf(ak[p]);
        vbuf[pt*128 + perm] = f2bf(av[p]);
    }
}

// ---------------------------------------------------------------------------
// Kernel 2b: KNN partial v5 — wave-uniform SCALAR candidate stream.
// cp provably wave-uniform (readfirstlane wave id + block-derived batch) so
// candidate loads go to the SMEM/SALU pipe; manual 2-group ping-pong removes
// all register copies. Cross-wave threshold sharing kept (safe pruning).
// ---------------------------------------------------------------------------
#define RINGN 15
#define RSTR 264
#define DRTH 8

__global__ __launch_bounds__(256, 4)
void knn_part_kernel(const float4* __restrict__ cand,
                     float* __restrict__ part_d, int* __restrict__ part_i)
{
    __shared__ float smem[8320];               // ring (pre-sync) / mg (post)
    __shared__ float thr_sh[4][64];            // per-wave published ad[15]
    float* ringd = smem;                       // [RINGN][RSTR] = 3960 floats
    int*   ringi = (int*)(smem + RINGN*RSTR);  // + 3960 = 7920 <= 8320
    float2* mg   = (float2*)smem;              // [64][65] (post-sync reuse)

    const int t  = threadIdx.x;
    const int ql = t & 63, wv = t >> 6;
    const int wv_u = __builtin_amdgcn_readfirstlane(wv);   // wave-uniform
    const int qsg = blockIdx.x >> 2;      // 0..255
    const int ck  = blockIdx.x & 3;       // chunk of 2048
    const int b_u = (qsg * 64) >> 13;     // batch id, block-uniform (64|8192)
    const int q   = qsg * 64 + ql;        // global query id

    const float4* cp = cand + (b_u << 13) + ck * 2048 + wv_u * 512; // scalar
    const int ibase = ck * 2048 + wv_u * 512;
    float4 qc = cand[(b_u << 13) + (q & 8191)];
    const float qx2 = -2.f * qc.x, qy2 = -2.f * qc.y, qz2 = -2.f * qc.z;

    thr_sh[wv][ql] = FLT_MAX;
    __syncthreads();

    float ad[16];
    int   ai[16];
    #pragma unroll
    for (int i = 0; i < 16; ++i) { ad[i] = FLT_MAX; ai[i] = -1; }
    int rc = 0;

    auto insert16 = [&](float d, int idx) {
        bool hi = true;
        #pragma unroll
        for (int sl = 15; sl >= 1; --sl) {
            bool sw = d < ad[sl-1];
            float nd = sw ? ad[sl-1] : (hi ? d   : ad[sl]);
            int   ni = sw ? ai[sl-1] : (hi ? idx : ai[sl]);
            ad[sl] = nd; ai[sl] = ni;
            hi = hi && sw;
        }
        ad[0] = hi ? d   : ad[0];
        ai[0] = hi ? idx : ai[0];
    };
    auto drain = [&]() {
        for (int w = 0; w < rc; ++w) {
            float d = ringd[w * RSTR + t];
            int idx = ringi[w * RSTR + t];
            if (d < ad[15]) insert16(d, idx);
        }
        rc = 0;
    };
    auto dist = [&](float4 c) {
        return fmaf(qx2, c.x, fmaf(qy2, c.y, fmaf(qz2, c.z, c.w)));
    };

    // seed: first 16 candidates of this wave's range
    #pragma unroll
    for (int m = 0; m < 16; ++m) insert16(dist(cp[m]), ibase + m);

    float Tcur = FLT_MAX;
    float4 A[8], Bv[8];
    #pragma unroll
    for (int u = 0; u < 8; ++u) A[u] = cp[16 + u];

    auto process = [&](const float4* G, int mbase) {
        float dv[8];
        #pragma unroll
        for (int u = 0; u < 8; ++u) dv[u] = dist(G[u]);
        float thr = fminf(ad[15], Tcur);
        int hm = 0;
        #pragma unroll
        for (int u = 0; u < 8; ++u) hm |= (dv[u] < thr) ? (1 << u) : 0;
        if (__any(hm != 0)) {
            #pragma unroll
            for (int u = 0; u < 8; ++u) {
                if (hm & (1 << u)) {
                    ringd[rc * RSTR + t] = dv[u];
                    ringi[rc * RSTR + t] = ibase + mbase + u;
                    ++rc;
                }
            }
            if (__any(rc >= DRTH)) drain();
        }
    };

    for (int m = 16; m < 512; m += 16) {
        if ((m & 31) == 16) {            // every 32 cands: publish + refresh
            thr_sh[wv][ql] = ad[15];
            Tcur = fminf(fminf(thr_sh[0][ql], thr_sh[1][ql]),
                         fminf(thr_sh[2][ql], thr_sh[3][ql]));
        }
        #pragma unroll
        for (int u = 0; u < 8; ++u) Bv[u] = cp[m + 8 + u];
        process(A, m);
        if (m + 16 < 512) {
            #pragma unroll
            for (int u = 0; u < 8; ++u) A[u] = cp[m + 16 + u];
        }
        process(Bv, m + 8);
    }
    drain();
    __syncthreads();

    #pragma unroll
    for (int i = 0; i < 16; ++i) {
        float2 e; e.x = ad[i]; e.y = __builtin_bit_cast(float, ai[i]);
        mg[ql * 65 + wv * 16 + i] = e;
    }
    __syncthreads();

    int rank[16];
    #pragma unroll
    for (int i = 0; i < 16; ++i) rank[i] = 0;
    for (int j = 0; j < 64; ++j) {
        float2 e = mg[ql * 65 + j];
        float dj = e.x; int ij = __builtin_bit_cast(int, e.y);
        #pragma unroll
        for (int i = 0; i < 16; ++i)
            rank[i] += ((dj < ad[i]) || (dj == ad[i] && ij < ai[i])) ? 1 : 0;
    }
    const long pb = ((long)q * 4 + ck) * 16;
    #pragma unroll
    for (int i = 0; i < 16; ++i)
        if (rank[i] < 16) {
            part_d[pb + rank[i]] = ad[i];
            part_i[pb + rank[i]] = ai[i];
        }
}

// ---------------------------------------------------------------------------
// Kernel 2c: merge 4 partial top-16 -> final top-16 (rank select, idx ties)
// ---------------------------------------------------------------------------
__global__ __launch_bounds__(256, 4)
void knn_merge_kernel(const float* __restrict__ part_d,
                      const int* __restrict__ part_i, int* __restrict__ knn)
{
    __shared__ float sd[4][64];
    __shared__ int   si[4][64];
    const int t = threadIdx.x;
    const int ql = t >> 6, e = t & 63;
    const long q = (long)blockIdx.x * 4 + ql;
    float d = part_d[q * 64 + e];
    int idx = part_i[q * 64 + e];
    sd[ql][e] = d; si[ql][e] = idx;
    __syncthreads();
    int rank = 0;
    #pragma unroll 8
    for (int j = 0; j < 64; ++j) {
        float dj = sd[ql][j];
        rank += ((dj < d) || (dj == d && si[ql][j] < idx)) ? 1 : 0;
    }
    if (rank < 16) knn[q * 16 + rank] = idx;
}

// ---------------------------------------------------------------------------
// Kernel 3: fused attention, MFMA 16x16x32 bf16 (unchanged).
// ---------------------------------------------------------------------------
__device__ inline int hswz(int r, int c) {           // hbuf swizzled index
    return r * 128 + (c ^ ((r & 7) << 4));
}

__global__ __launch_bounds__(256, 2)
void attn_kernel(const float* __restrict__ xyz, const float* __restrict__ feat,
                 const float* __restrict__ d1_w, const float* __restrict__ d1_b,
                 const float* __restrict__ d2_b, const float* __restrict__ g1_b,
                 const float* __restrict__ g2_b,
                 const float* __restrict__ fc2_w, const float* __restrict__ fc2_b,
                 const unsigned short* __restrict__ qb,
                 const unsigned short* __restrict__ kb,
                 const unsigned short* __restrict__ vb,
                 const unsigned short* __restrict__ wd2,
                 const unsigned short* __restrict__ wg1,
                 const unsigned short* __restrict__ wg2,
                 const int* __restrict__ knn, float* __restrict__ out)
{
    __shared__ unsigned short hbuf[128 * 128];  // h1 -> h -> gh (swizzled)
    __shared__ float relb[128 * 4];
    __shared__ float resl[8 * 128];
    __shared__ int   idxs[128];

    const int t    = threadIdx.x;
    const int wave = t >> 6, lane = t & 63;
    const int quad = lane >> 4, l15 = lane & 15;
    const long pbase = (long)blockIdx.x * 8;
    const int b = (int)(pbase >> 13);
    const long bofs = (long)b * NPTS;

    if (t < 128) idxs[t] = knn[(pbase + (t >> 4)) * 16 + (t & 15)];
    __syncthreads();

    if (t < 128) {
        int r = t;
        int nn = (int)((pbase + (r >> 4)) & 8191);
        int m = idxs[r];
        const float* xg = xyz + (long)b * 3 * NPTS;
        relb[r*4+0] = xg[nn]        - xg[m];
        relb[r*4+1] = xg[NPTS+nn]   - xg[NPTS+m];
        relb[r*4+2] = xg[2*NPTS+nn] - xg[2*NPTS+m];
        relb[r*4+3] = 0.f;
    }
    short8 qvv[2], kgv[2][4], vgv[2][4];
    #pragma unroll
    for (int mt = 0; mt < 2; ++mt) {
        qvv[mt] = *(const short8*)(qb + (size_t)(pbase + wave*2 + mt) * 128 + l15*8);
        #pragma unroll
        for (int r = 0; r < 4; ++r) {
            int R = (wave*2 + mt)*16 + quad*4 + r;
            kgv[mt][r] = *(const short8*)(kb + (size_t)(bofs + idxs[R]) * 128 + l15*8);
            vgv[mt][r] = *(const short8*)(vb + (size_t)(bofs + idxs[R]) * 128 + l15*8);
        }
    }
    __syncthreads();

    {
        int c8 = t & 15, r0 = t >> 4;
        float w0[8], w1[8], w2[8], bb[8];
        #pragma unroll
        for (int k = 0; k < 8; ++k) {
            int c = c8*8 + k;
            w0[k] = d1_w[c*3]; w1[k] = d1_w[c*3+1]; w2[k] = d1_w[c*3+2];
            bb[k] = d1_b[c];
        }
        #pragma unroll
        for (int i = 0; i < 8; ++i) {
            int row = r0 + 16*i;
            float4 rl = *(const float4*)&relb[row*4];
            short8 hv;
            #pragma unroll
            for (int k = 0; k < 8; ++k) {
                float v = fmaf(w0[k], rl.x, fmaf(w1[k], rl.y, fmaf(w2[k], rl.z, bb[k])));
                hv[k] = (short)f2bf(fmaxf(v, 0.f));
            }
            *(short8*)&hbuf[hswz(row, c8*8)] = hv;
        }
    }
    __syncthreads();

    const int wrow0 = wave * 32;
    short8 A[2][4];
    f32x4 acc[2];

    auto loadA = [&]() {
        #pragma unroll
        for (int mt = 0; mt < 2; ++mt)
            #pragma unroll
            for (int kk = 0; kk < 4; ++kk)
                A[mt][kk] = *(const short8*)&hbuf[hswz(wrow0 + mt*16 + l15, kk*32 + quad*8)];
    };

    unsigned posp[2][8][2];   // packed bf16 pos fragments

    // ============ GEMM 1: pos = h1 @ d2.T + b; h = q - kg + pos ============
    loadA();
    #pragma unroll
    for (int n0 = 0; n0 < 8; ++n0) {
        const unsigned short* wp = wd2 + (n0*16 + l15) * 128 + quad*8;
        short8 B0 = *(const short8*)(wp);
        short8 B1 = *(const short8*)(wp + 32);
        short8 B2 = *(const short8*)(wp + 64);
        short8 B3 = *(const short8*)(wp + 96);
        acc[0] = (f32x4){0.f,0.f,0.f,0.f};
        acc[1] = (f32x4){0.f,0.f,0.f,0.f};
        #pragma unroll
        for (int mt = 0; mt < 2; ++mt) {
            acc[mt] = __builtin_amdgcn_mfma_f32_16x16x32_bf16(A[mt][0], B0, acc[mt], 0, 0, 0);
            acc[mt] = __builtin_amdgcn_mfma_f32_16x16x32_bf16(A[mt][1], B1, acc[mt], 0, 0, 0);
            acc[mt] = __builtin_amdgcn_mfma_f32_16x16x32_bf16(A[mt][2], B2, acc[mt], 0, 0, 0);
            acc[mt] = __builtin_amdgcn_mfma_f32_16x16x32_bf16(A[mt][3], B3, acc[mt], 0, 0, 0);
        }
        int c = n0*16 + l15;
        float bb = d2_b[c];
        #pragma unroll
        for (int mt = 0; mt < 2; ++mt) {
            float qv = bf2f((unsigned short)qvv[mt][n0]);
            float p0 = acc[mt][0] + bb, p1 = acc[mt][1] + bb;
            float p2 = acc[mt][2] + bb, p3 = acc[mt][3] + bb;
            posp[mt][n0][0] = (unsigned)f2bf(p0) | ((unsigned)f2bf(p1) << 16);
            posp[mt][n0][1] = (unsigned)f2bf(p2) | ((unsigned)f2bf(p3) << 16);
            int rb = wrow0 + mt*16 + quad*4;
            hbuf[hswz(rb+0, c)] = f2bf(qv - bf2f((unsigned short)kgv[mt][0][n0]) + p0);
            hbuf[hswz(rb+1, c)] = f2bf(qv - bf2f((unsigned short)kgv[mt][1][n0]) + p1);
            hbuf[hswz(rb+2, c)] = f2bf(qv - bf2f((unsigned short)kgv[mt][2][n0]) + p2);
            hbuf[hswz(rb+3, c)] = f2bf(qv - bf2f((unsigned short)kgv[mt][3][n0]) + p3);
        }
    }

    // ============ GEMM 2: gh = relu(h @ g1.T + b) ============
    loadA();
    #pragma unroll
    for (int n0 = 0; n0 < 8; ++n0) {
        const unsigned short* wp = wg1 + (n0*16 + l15) * 128 + quad*8;
        short8 B0 = *(const short8*)(wp);
        short8 B1 = *(const short8*)(wp + 32);
        short8 B2 = *(const short8*)(wp + 64);
        short8 B3 = *(const short8*)(wp + 96);
        acc[0] = (f32x4){0.f,0.f,0.f,0.f};
        acc[1] = (f32x4){0.f,0.f,0.f,0.f};
        #pragma unroll
        for (int mt = 0; mt < 2; ++mt) {
            acc[mt] = __builtin_amdgcn_mfma_f32_16x16x32_bf16(A[mt][0], B0, acc[mt], 0, 0, 0);
            acc[mt] = __builtin_amdgcn_mfma_f32_16x16x32_bf16(A[mt][1], B1, acc[mt], 0, 0, 0);
            acc[mt] = __builtin_amdgcn_mfma_f32_16x16x32_bf16(A[mt][2], B2, acc[mt], 0, 0, 0);
            acc[mt] = __builtin_amdgcn_mfma_f32_16x16x32_bf16(A[mt][3], B3, acc[mt], 0, 0, 0);
        }
        int c = n0*16 + l15;
        float bb = g1_b[c];
        #pragma unroll
        for (int mt = 0; mt < 2; ++mt) {
            int rb = wrow0 + mt*16 + quad*4;
            #pragma unroll
            for (int r = 0; r < 4; ++r)
                hbuf[hswz(rb+r, c)] = f2bf(fmaxf(acc[mt][r] + bb, 0.f));
        }
    }

    // ==== GEMM 3: logits -> softmax over K -> res = sum attn*(v+pos) ====
    loadA();
    const float sc = 0.08838834764831845f;
    #pragma unroll
    for (int n0 = 0; n0 < 8; ++n0) {
        const unsigned short* wp = wg2 + (n0*16 + l15) * 128 + quad*8;
        short8 B0 = *(const short8*)(wp);
        short8 B1 = *(const short8*)(wp + 32);
        short8 B2 = *(const short8*)(wp + 64);
        short8 B3 = *(const short8*)(wp + 96);
        acc[0] = (f32x4){0.f,0.f,0.f,0.f};
        acc[1] = (f32x4){0.f,0.f,0.f,0.f};
        #pragma unroll
        for (int mt = 0; mt < 2; ++mt) {
            acc[mt] = __builtin_amdgcn_mfma_f32_16x16x32_bf16(A[mt][0], B0, acc[mt], 0, 0, 0);
            acc[mt] = __builtin_amdgcn_mfma_f32_16x16x32_bf16(A[mt][1], B1, acc[mt], 0, 0, 0);
            acc[mt] = __builtin_amdgcn_mfma_f32_16x16x32_bf16(A[mt][2], B2, acc[mt], 0, 0, 0);
            acc[mt] = __builtin_amdgcn_mfma_f32_16x16x32_bf16(A[mt][3], B3, acc[mt], 0, 0, 0);
        }
        int c = n0*16 + l15;
        float bb = g2_b[c];
        #pragma unroll
        for (int mt = 0; mt < 2; ++mt) {
            float e0 = (acc[mt][0] + bb) * sc;
            float e1 = (acc[mt][1] + bb) * sc;
            float e2 = (acc[mt][2] + bb) * sc;
            float e3 = (acc[mt][3] + bb) * sc;
            float mx = fmaxf(fmaxf(e0, e1), fmaxf(e2, e3));
            mx = fmaxf(mx, __shfl_xor(mx, 16));
            mx = fmaxf(mx, __shfl_xor(mx, 32));
            e0 = __expf(e0 - mx); e1 = __expf(e1 - mx);
            e2 = __expf(e2 - mx); e3 = __expf(e3 - mx);
            float ssum = e0 + e1 + e2 + e3;
            ssum += __shfl_xor(ssum, 16);
            ssum += __shfl_xor(ssum, 32);
            float p0 = bf2f((unsigned short)(posp[mt][n0][0] & 0xffff));
            float p1 = bf2f((unsigned short)(posp[mt][n0][0] >> 16));
            float p2 = bf2f((unsigned short)(posp[mt][n0][1] & 0xffff));
            float p3 = bf2f((unsigned short)(posp[mt][n0][1] >> 16));
            float p = e0 * (bf2f((unsigned short)vgv[mt][0][n0]) + p0)
                    + e1 * (bf2f((unsigned short)vgv[mt][1][n0]) + p1)
                    + e2 * (bf2f((unsigned short)vgv[mt][2][n0]) + p2)
                    + e3 * (bf2f((unsigned short)vgv[mt][3][n0]) + p3);
            p += __shfl_xor(p, 16);
            p += __shfl_xor(p, 32);
            if (quad == 0) resl[(wave*2 + mt)*128 + c] = p / ssum;
        }
    }
    __syncthreads();

    // ---- epilogue: out = res @ fc2.T + b + feat ----
    {
        int pt = t >> 5, j = t & 31;
        #pragma unroll
        for (int dp = 0; dp < 3; ++dp) {
            float part = 0.f;
            #pragma unroll
            for (int i = 0; i < 4; ++i) {
                int cc = j + 32*i;
                part = fmaf(fc2_w[dp*128 + cc], resl[pt*128 + cc], part);
            }
            part += __shfl_down(part, 16, 32);
            part += __shfl_down(part, 8, 32);
            part += __shfl_down(part, 4, 32);
            part += __shfl_down(part, 2, 32);
            part += __shfl_down(part, 1, 32);
            if (j == 0) {
                int nn = (int)((pbase + pt) & 8191);
                long o = ((long)b*3 + dp) * NPTS + nn;
                out[o] = part + fc2_b[dp] + feat[o];
            }
        }
    }
}

// ---------------------------------------------------------------------------
extern "C" void kernel_launch(void* const* d_in, const int* in_sizes, int n_in,
                              void* d_out, int out_size, void* d_ws, size_t ws_size,
                              hipStream_t stream)
{
    const float* xyz   = (const float*)d_in[0];
    const float* feat  = (const float*)d_in[1];
    const float* fc1_w = (const float*)d_in[2];
    const float* fc1_b = (const float*)d_in[3];
    const float* fc2_w = (const float*)d_in[4];
    const float* fc2_b = (const float*)d_in[5];
    const float* d1_w  = (const float*)d_in[6];
    const float* d1_b  = (const float*)d_in[7];
    const float* d2_w  = (const float*)d_in[8];
    const float* d2_b  = (const float*)d_in[9];
    const float* g1_w  = (const float*)d_in[10];
    const float* g1_b  = (const float*)d_in[11];
    const float* g2_w  = (const float*)d_in[12];
    const float* g2_b  = (const float*)d_in[13];
    const float* wq_w  = (const float*)d_in[14];
    const float* wk_w  = (const float*)d_in[15];
    const float* wv_w  = (const float*)d_in[16];
    float* out = (float*)d_out;

    unsigned short* qb  = (unsigned short*)d_ws;      // 16384*128 bf16 (permuted)
    unsigned short* kb  = qb + (size_t)16384*128;
    unsigned short* vb  = kb + (size_t)16384*128;
    unsigned short* wd2 = vb + (size_t)16384*128;     // 128*128 bf16 each
    unsigned short* wg1 = wd2 + 16384;
    unsigned short* wg2 = wg1 + 16384;
    int*   knn_ws = (int*)(wg2 + 16384);              // 16384*16 i32
    float4* cand  = (float4*)(knn_ws + (size_t)16384*16);   // 16384 float4
    float* part_d = (float*)(cand + 16384);           // 16384*64 f32
    int*   part_i = (int*)(part_d + (size_t)16384*64);// 16384*64 i32

    hipLaunchKernelGGL(prep_kernel, dim3(256), dim3(256), 0, stream,
                       d2_w, g1_w, g2_w, wd2, wg1, wg2, xyz, cand);
    hipLaunchKernelGGL(knn_part_kernel, dim3(1024), dim3(256), 0, stream,
                       cand, part_d, part_i);
    hipLaunchKernelGGL(knn_merge_kernel, dim3(4096), dim3(256), 0, stream,
                       part_d, part_i, knn_ws);
    hipLaunchKernelGGL(proj_kernel, dim3(2048), dim3(128), 0, stream,
                       feat, fc1_w, fc1_b, wq_w, wk_w, wv_w, qb, kb, vb);
    hipLaunchKernelGGL(attn_kernel, dim3(2048), dim3(256), 0, stream,
                       xyz, feat, d1_w, d1_b, d2_b, g1_b, g2_b, fc2_w, fc2_b,
                       qb, kb, vb, wd2, wg1, wg2, knn_ws, out);
}